// Round 1
// baseline (525.577 us; speedup 1.0000x reference)
//
#include <hip/hip_runtime.h>
#include <hip/hip_bf16.h>

#define LSEQ 20000
#define DEG  16
#define F    128
#define ALPHA 0.2f

// Kernel 1: y16 = bf16(x @ W); s1 = (xW)·a1, s2 = (xW)·a2 (fp32)
// Block = 128 threads (2 waves), 64 rows per block. Thread owns output
// column c: W[:,c] lives in 128 VGPRs; x row values are wave-uniform
// (expect s_load), so the inner loop is pure v_fmac with SGPR operand.
__global__ __launch_bounds__(128) void gat_gemm(const float* __restrict__ x,
                                                const float* __restrict__ W,
                                                const float* __restrict__ a,
                                                __hip_bfloat16* __restrict__ y16,
                                                float* __restrict__ s1,
                                                float* __restrict__ s2)
{
    const int c    = threadIdx.x;       // 0..127 output column
    const int lane = c & 63;
    const int wid  = c >> 6;
    const int row0 = blockIdx.x * 64;

    float wcol[F];
    #pragma unroll
    for (int k = 0; k < F; ++k) wcol[k] = W[k * F + c];

    const float a1c = a[c];
    const float a2c = a[F + c];

    __shared__ float lp1[2][64];
    __shared__ float lp2[2][64];

    for (int r = 0; r < 64; r += 4) {
        const float* xr = x + (size_t)(row0 + r) * F;
        float acc0 = 0.f, acc1 = 0.f, acc2 = 0.f, acc3 = 0.f;
        #pragma unroll
        for (int k = 0; k < F; ++k) {
            const float wk = wcol[k];
            acc0 = fmaf(xr[k],       wk, acc0);
            acc1 = fmaf(xr[F + k],   wk, acc1);
            acc2 = fmaf(xr[2*F + k], wk, acc2);
            acc3 = fmaf(xr[3*F + k], wk, acc3);
        }
        size_t yb = (size_t)(row0 + r) * F + c;
        y16[yb]       = __float2bfloat16(acc0);
        y16[yb + F]   = __float2bfloat16(acc1);
        y16[yb + 2*F] = __float2bfloat16(acc2);
        y16[yb + 3*F] = __float2bfloat16(acc3);

        // s1/s2 partials: reduce over the 128 columns (2 waves)
        float p10 = acc0 * a1c, p11 = acc1 * a1c, p12 = acc2 * a1c, p13 = acc3 * a1c;
        float p20 = acc0 * a2c, p21 = acc1 * a2c, p22 = acc2 * a2c, p23 = acc3 * a2c;
        #pragma unroll
        for (int off = 32; off; off >>= 1) {
            p10 += __shfl_xor(p10, off); p11 += __shfl_xor(p11, off);
            p12 += __shfl_xor(p12, off); p13 += __shfl_xor(p13, off);
            p20 += __shfl_xor(p20, off); p21 += __shfl_xor(p21, off);
            p22 += __shfl_xor(p22, off); p23 += __shfl_xor(p23, off);
        }
        if (lane == 0) {
            lp1[wid][r] = p10; lp1[wid][r+1] = p11; lp1[wid][r+2] = p12; lp1[wid][r+3] = p13;
            lp2[wid][r] = p20; lp2[wid][r+1] = p21; lp2[wid][r+2] = p22; lp2[wid][r+3] = p23;
        }
    }
    __syncthreads();
    if (c < 64) {
        s1[row0 + c] = lp1[0][c] + lp1[1][c];
    } else {
        const int i = c - 64;
        s2[row0 + i] = lp2[0][i] + lp2[1][i];
    }
}

// Kernel 2: one wave per (b,l). e_d = s1[adj_d] + s2[adj_0]; softmax over
// leaky_relu(e); out = elu(sum_d attn_d * y16[adj_d]). Lane holds 2 columns.
__global__ __launch_bounds__(256) void gat_attn(const int* __restrict__ adj,
                                                const __hip_bfloat16* __restrict__ y16,
                                                const float* __restrict__ s1,
                                                const float* __restrict__ s2,
                                                float* __restrict__ out)
{
    const int lane = threadIdx.x & 63;
    const int wid  = threadIdx.x >> 6;
    const int gl   = blockIdx.x * 4 + wid;      // flat (b,l)
    const int b    = gl / LSEQ;
    const int base = b * LSEQ;

    const int* adjp = adj + (size_t)gl * DEG;
    int av = (lane < DEG) ? adjp[lane] : 0;

    float sv = (lane < DEG) ? s1[base + av] : 0.f;
    const int a0 = __shfl(av, 0);
    const float e = sv + s2[base + a0];
    const float t = e > 0.f ? e : ALPHA * e;

    // softmax over lanes 0..15 (shuffles stay inside the 16-lane group)
    float m = t;
    #pragma unroll
    for (int off = 8; off; off >>= 1) m = fmaxf(m, __shfl_xor(m, off));
    float w = (lane < DEG) ? __expf(t - m) : 0.f;
    float p = w;
    #pragma unroll
    for (int off = 8; off; off >>= 1) p += __shfl_xor(p, off);
    const float attn = w / p;   // valid on lanes 0..15 (only those are read)

    float accx = 0.f, accy = 0.f;
    #pragma unroll
    for (int d = 0; d < DEG; ++d) {
        const float ad = __shfl(attn, d);
        const int   nb = __shfl(av, d);
        const unsigned int v =
            reinterpret_cast<const unsigned int*>(y16 + (size_t)(base + nb) * F)[lane];
        const float lo = __uint_as_float(v << 16);          // column 2*lane
        const float hi = __uint_as_float(v & 0xffff0000u);  // column 2*lane+1
        accx = fmaf(ad, lo, accx);
        accy = fmaf(ad, hi, accy);
    }
    const float ox = accx > 0.f ? accx : __expf(accx) - 1.f;
    const float oy = accy > 0.f ? accy : __expf(accy) - 1.f;
    *reinterpret_cast<float2*>(out + (size_t)gl * F + lane * 2) = make_float2(ox, oy);
}

extern "C" void kernel_launch(void* const* d_in, const int* in_sizes, int n_in,
                              void* d_out, int out_size, void* d_ws, size_t ws_size,
                              hipStream_t stream) {
    const float* x   = (const float*)d_in[0];
    const int*   adj = (const int*)d_in[1];
    const float* W   = (const float*)d_in[2];
    const float* a   = (const float*)d_in[3];
    float* out = (float*)d_out;

    const int BL = in_sizes[0] / F;   // bs*L = 80000

    __hip_bfloat16* y16 = (__hip_bfloat16*)d_ws;
    float* s1 = (float*)((char*)d_ws + (size_t)BL * F * sizeof(__hip_bfloat16));
    float* s2 = s1 + BL;

    gat_gemm<<<BL / 64, 128, 0, stream>>>(x, W, a, y16, s1, s2);
    gat_attn<<<BL / 4, 256, 0, stream>>>(adj, y16, s1, s2, out);
}

// Round 2
// 166.146 us; speedup vs baseline: 3.1633x; 3.1633x over previous
//
#include <hip/hip_runtime.h>
#include <hip/hip_bf16.h>

#define LSEQ 20000
#define DEG  16
#define F    128
#define TM   64
#define ALPHA 0.2f

// Kernel 1: y16 = bf16(x @ W); s1 = (xW)·a1, s2 = (xW)·a2 (fp32 accumulate).
// Block = 256 threads (4 waves). Tile: 64 rows x 128 cols, K=128 in one pass.
// x tile staged in LDS (32 KB); W streamed from global (L1/L2 resident).
// Thread (cl = t&63, rg = t>>6) owns cols {2cl, 2cl+1} for rows rg*16..+15.
// acc = 32 VGPRs -> high occupancy (LDS-limited at 5 blocks/CU).
__global__ __launch_bounds__(256) void gat_gemm(const float* __restrict__ x,
                                                const float* __restrict__ W,
                                                const float* __restrict__ a,
                                                __hip_bfloat16* __restrict__ y16,
                                                float* __restrict__ s1,
                                                float* __restrict__ s2)
{
    __shared__ float xs[TM][F];                 // 32 KB
    const int t    = threadIdx.x;
    const int row0 = blockIdx.x * TM;

    // Cooperative coalesced load of the x tile: 8192 floats = 2048 float4.
    {
        const float4* xg  = reinterpret_cast<const float4*>(x + (size_t)row0 * F);
        float4*       xsv = reinterpret_cast<float4*>(&xs[0][0]);
        #pragma unroll
        for (int i = 0; i < 8; ++i) xsv[t + 256 * i] = xg[t + 256 * i];
    }
    __syncthreads();

    const int cl = t & 63;
    const int rg = t >> 6;
    const int c0 = cl * 2;

    const float2 a1 = *reinterpret_cast<const float2*>(a + c0);
    const float2 a2 = *reinterpret_cast<const float2*>(a + F + c0);

    float acc[16][2];
    #pragma unroll
    for (int r = 0; r < 16; ++r) { acc[r][0] = 0.f; acc[r][1] = 0.f; }

    const float* xrow = &xs[rg * 16][0];

    for (int k4 = 0; k4 < F; k4 += 4) {
        const float2 w0 = *reinterpret_cast<const float2*>(W + (size_t)(k4 + 0) * F + c0);
        const float2 w1 = *reinterpret_cast<const float2*>(W + (size_t)(k4 + 1) * F + c0);
        const float2 w2 = *reinterpret_cast<const float2*>(W + (size_t)(k4 + 2) * F + c0);
        const float2 w3 = *reinterpret_cast<const float2*>(W + (size_t)(k4 + 3) * F + c0);
        #pragma unroll
        for (int r = 0; r < 16; ++r) {
            const float4 xq = *reinterpret_cast<const float4*>(xrow + r * F + k4);
            acc[r][0] = fmaf(xq.x, w0.x, acc[r][0]); acc[r][1] = fmaf(xq.x, w0.y, acc[r][1]);
            acc[r][0] = fmaf(xq.y, w1.x, acc[r][0]); acc[r][1] = fmaf(xq.y, w1.y, acc[r][1]);
            acc[r][0] = fmaf(xq.z, w2.x, acc[r][0]); acc[r][1] = fmaf(xq.z, w2.y, acc[r][1]);
            acc[r][0] = fmaf(xq.w, w3.x, acc[r][0]); acc[r][1] = fmaf(xq.w, w3.y, acc[r][1]);
        }
    }

    // Epilogue: bf16 pack + coalesced y16 store; wave-wide reduce for s1/s2.
    const int rbase = row0 + rg * 16;
    #pragma unroll
    for (int r = 0; r < 16; ++r) {
        union { __hip_bfloat162 h2; unsigned int u; } cv;
        cv.h2 = __float22bfloat162_rn(make_float2(acc[r][0], acc[r][1]));
        reinterpret_cast<unsigned int*>(y16 + (size_t)(rbase + r) * F)[cl] = cv.u;

        float p1 = fmaf(acc[r][0], a1.x, acc[r][1] * a1.y);
        float p2 = fmaf(acc[r][0], a2.x, acc[r][1] * a2.y);
        #pragma unroll
        for (int off = 32; off; off >>= 1) {
            p1 += __shfl_xor(p1, off);
            p2 += __shfl_xor(p2, off);
        }
        if (cl == 0) {
            s1[rbase + r] = p1;
            s2[rbase + r] = p2;
        }
    }
}

// Kernel 2: one wave per (b,l). e_d = s1[adj_d] + s2[adj_0]; softmax over
// leaky_relu(e); out = elu(sum_d attn_d * y16[adj_d]). Lane holds 2 columns.
__global__ __launch_bounds__(256) void gat_attn(const int* __restrict__ adj,
                                                const __hip_bfloat16* __restrict__ y16,
                                                const float* __restrict__ s1,
                                                const float* __restrict__ s2,
                                                float* __restrict__ out)
{
    const int lane = threadIdx.x & 63;
    const int wid  = threadIdx.x >> 6;
    const int gl   = blockIdx.x * 4 + wid;      // flat (b,l)
    const int b    = gl / LSEQ;
    const int base = b * LSEQ;

    const int* adjp = adj + (size_t)gl * DEG;
    int av = (lane < DEG) ? adjp[lane] : 0;

    float sv = (lane < DEG) ? s1[base + av] : 0.f;
    const int a0 = __shfl(av, 0);
    const float e = sv + s2[base + a0];
    const float t = e > 0.f ? e : ALPHA * e;

    // softmax over lanes 0..15 (shuffles stay inside the 16-lane group)
    float m = t;
    #pragma unroll
    for (int off = 8; off; off >>= 1) m = fmaxf(m, __shfl_xor(m, off));
    float w = (lane < DEG) ? __expf(t - m) : 0.f;
    float p = w;
    #pragma unroll
    for (int off = 8; off; off >>= 1) p += __shfl_xor(p, off);
    const float attn = w / p;   // valid on lanes 0..15 (only those are read)

    float accx = 0.f, accy = 0.f;
    #pragma unroll
    for (int d = 0; d < DEG; ++d) {
        const float ad = __shfl(attn, d);
        const int   nb = __shfl(av, d);
        const unsigned int v =
            reinterpret_cast<const unsigned int*>(y16 + (size_t)(base + nb) * F)[lane];
        const float lo = __uint_as_float(v << 16);          // column 2*lane
        const float hi = __uint_as_float(v & 0xffff0000u);  // column 2*lane+1
        accx = fmaf(ad, lo, accx);
        accy = fmaf(ad, hi, accy);
    }
    const float ox = accx > 0.f ? accx : __expf(accx) - 1.f;
    const float oy = accy > 0.f ? accy : __expf(accy) - 1.f;
    *reinterpret_cast<float2*>(out + (size_t)gl * F + lane * 2) = make_float2(ox, oy);
}

extern "C" void kernel_launch(void* const* d_in, const int* in_sizes, int n_in,
                              void* d_out, int out_size, void* d_ws, size_t ws_size,
                              hipStream_t stream) {
    const float* x   = (const float*)d_in[0];
    const int*   adj = (const int*)d_in[1];
    const float* W   = (const float*)d_in[2];
    const float* a   = (const float*)d_in[3];
    float* out = (float*)d_out;

    const int BL = in_sizes[0] / F;   // bs*L = 80000

    __hip_bfloat16* y16 = (__hip_bfloat16*)d_ws;
    float* s1 = (float*)((char*)d_ws + (size_t)BL * F * sizeof(__hip_bfloat16));
    float* s2 = s1 + BL;

    gat_gemm<<<BL / TM, 256, 0, stream>>>(x, W, a, y16, s1, s2);
    gat_attn<<<BL / 4, 256, 0, stream>>>(adj, y16, s1, s2, out);
}

// Round 3
// 150.979 us; speedup vs baseline: 3.4811x; 1.1005x over previous
//
#include <hip/hip_runtime.h>
#include <hip/hip_bf16.h>

#define LSEQ 20000
#define DEG  16
#define F    128
#define ALPHA 0.2f

typedef __bf16 bf16x8 __attribute__((ext_vector_type(8)));
typedef float  f32x4  __attribute__((ext_vector_type(4)));

// W^T as bf16: wt[n*F + k] = bf16(W[k*F + n]). 32 KB, L1-resident in gemm.
__global__ __launch_bounds__(256) void gat_wt(const float* __restrict__ W,
                                              __hip_bfloat16* __restrict__ wt)
{
    for (int i = blockIdx.x * 256 + threadIdx.x; i < F * F; i += 16 * 256) {
        const int k = i >> 7, n = i & (F - 1);
        wt[n * F + k] = __float2bfloat16(W[i]);
    }
}

// MFMA gemm: y16 = bf16(x @ W), s1 = (xW)·a1, s2 = (xW)·a2.
// One wave per 16-row stripe, no LDS. A-frag: A[m=lane&15][k=(lane>>4)*8+j]
// (fp32 load + cvt). B-frag: W[k][n=lane&15] = wt[n][k] contiguous 16B.
// D: col=lane&15, row=(lane>>4)*4+reg (m89-verified layout).
__global__ __launch_bounds__(256) void gat_gemm(const float* __restrict__ x,
                                                const __hip_bfloat16* __restrict__ wt,
                                                const float* __restrict__ a,
                                                __hip_bfloat16* __restrict__ y16,
                                                float* __restrict__ s1,
                                                float* __restrict__ s2)
{
    const int lane   = threadIdx.x & 63;
    const int stripe = (blockIdx.x * 256 + threadIdx.x) >> 6;
    const int row0   = stripe * 16;
    const int m      = lane & 15;   // A row within stripe / D col
    const int q      = lane >> 4;   // quad group

    // A fragments for all 4 K-chunks: 16 rows x 128 k per wave.
    bf16x8 afr[4];
    const float* xr = x + (size_t)(row0 + m) * F + q * 8;
    #pragma unroll
    for (int kt = 0; kt < 4; ++kt) {
        const float4 q0 = *reinterpret_cast<const float4*>(xr + kt * 32);
        const float4 q1 = *reinterpret_cast<const float4*>(xr + kt * 32 + 4);
        bf16x8 f;
        f[0] = (__bf16)q0.x; f[1] = (__bf16)q0.y; f[2] = (__bf16)q0.z; f[3] = (__bf16)q0.w;
        f[4] = (__bf16)q1.x; f[5] = (__bf16)q1.y; f[6] = (__bf16)q1.z; f[7] = (__bf16)q1.w;
        afr[kt] = f;
    }

    float p1[4] = {0.f, 0.f, 0.f, 0.f};
    float p2[4] = {0.f, 0.f, 0.f, 0.f};
    const __hip_bfloat16* wb = wt + (size_t)m * F + q * 8;

    #pragma unroll 2
    for (int ct = 0; ct < 8; ++ct) {
        f32x4 acc = {0.f, 0.f, 0.f, 0.f};
        #pragma unroll
        for (int kt = 0; kt < 4; ++kt) {
            union { uint4 u; bf16x8 v; } b;
            b.u = *reinterpret_cast<const uint4*>(wb + (size_t)ct * 16 * F + kt * 32);
            acc = __builtin_amdgcn_mfma_f32_16x16x32_bf16(afr[kt], b.v, acc, 0, 0, 0);
        }
        const int col = ct * 16 + m;
        const float a1v = a[col];
        const float a2v = a[F + col];
        #pragma unroll
        for (int r = 0; r < 4; ++r) {
            const int row = row0 + q * 4 + r;
            y16[(size_t)row * F + col] = __float2bfloat16(acc[r]);
            p1[r] = fmaf(acc[r], a1v, p1[r]);
            p2[r] = fmaf(acc[r], a2v, p2[r]);
        }
    }

    // Reduce s1/s2 partials across the 16 cols held by lanes of each quad group.
    #pragma unroll
    for (int r = 0; r < 4; ++r) {
        #pragma unroll
        for (int off = 1; off < 16; off <<= 1) {
            p1[r] += __shfl_xor(p1[r], off);
            p2[r] += __shfl_xor(p2[r], off);
        }
    }
    if (m == 0) {
        #pragma unroll
        for (int r = 0; r < 4; ++r) {
            s1[row0 + q * 4 + r] = p1[r];
            s2[row0 + q * 4 + r] = p2[r];
        }
    }
}

// Kernel 2: one wave per (b,l). e_d = s1[adj_d] + s2[adj_0]; softmax over
// leaky_relu(e); out = elu(sum_d attn_d * y16[adj_d]). Lane holds 2 columns.
__global__ __launch_bounds__(256) void gat_attn(const int* __restrict__ adj,
                                                const __hip_bfloat16* __restrict__ y16,
                                                const float* __restrict__ s1,
                                                const float* __restrict__ s2,
                                                float* __restrict__ out)
{
    const int lane = threadIdx.x & 63;
    const int wid  = threadIdx.x >> 6;
    const int gl   = blockIdx.x * 4 + wid;      // flat (b,l)
    const int b    = gl / LSEQ;
    const int base = b * LSEQ;

    const int* adjp = adj + (size_t)gl * DEG;
    int av = (lane < DEG) ? adjp[lane] : 0;

    float sv = (lane < DEG) ? s1[base + av] : 0.f;
    const int a0 = __shfl(av, 0);
    const float e = sv + s2[base + a0];
    const float t = e > 0.f ? e : ALPHA * e;

    // softmax over lanes 0..15 (shuffles stay inside the 16-lane group)
    float m = t;
    #pragma unroll
    for (int off = 8; off; off >>= 1) m = fmaxf(m, __shfl_xor(m, off));
    float w = (lane < DEG) ? __expf(t - m) : 0.f;
    float p = w;
    #pragma unroll
    for (int off = 8; off; off >>= 1) p += __shfl_xor(p, off);
    const float attn = w / p;   // valid on lanes 0..15 (only those are read)

    float accx = 0.f, accy = 0.f;
    #pragma unroll
    for (int d = 0; d < DEG; ++d) {
        const float ad = __shfl(attn, d);
        const int   nb = __shfl(av, d);
        const unsigned int v =
            reinterpret_cast<const unsigned int*>(y16 + (size_t)(base + nb) * F)[lane];
        const float lo = __uint_as_float(v << 16);          // column 2*lane
        const float hi = __uint_as_float(v & 0xffff0000u);  // column 2*lane+1
        accx = fmaf(ad, lo, accx);
        accy = fmaf(ad, hi, accy);
    }
    const float ox = accx > 0.f ? accx : __expf(accx) - 1.f;
    const float oy = accy > 0.f ? accy : __expf(accy) - 1.f;
    *reinterpret_cast<float2*>(out + (size_t)gl * F + lane * 2) = make_float2(ox, oy);
}

extern "C" void kernel_launch(void* const* d_in, const int* in_sizes, int n_in,
                              void* d_out, int out_size, void* d_ws, size_t ws_size,
                              hipStream_t stream) {
    const float* x   = (const float*)d_in[0];
    const int*   adj = (const int*)d_in[1];
    const float* W   = (const float*)d_in[2];
    const float* a   = (const float*)d_in[3];
    float* out = (float*)d_out;

    const int BL = in_sizes[0] / F;   // bs*L = 80000

    __hip_bfloat16* y16 = (__hip_bfloat16*)d_ws;
    float* s1 = (float*)((char*)d_ws + (size_t)BL * F * sizeof(__hip_bfloat16));
    float* s2 = s1 + BL;
    __hip_bfloat16* wt = (__hip_bfloat16*)(s2 + BL);

    gat_wt  <<<16, 256, 0, stream>>>(W, wt);
    gat_gemm<<<BL / 64, 256, 0, stream>>>(x, wt, a, y16, s1, s2);
    gat_attn<<<BL / 4, 256, 0, stream>>>(adj, y16, s1, s2, out);
}

// Round 4
// 145.082 us; speedup vs baseline: 3.6226x; 1.0406x over previous
//
#include <hip/hip_runtime.h>
#include <hip/hip_bf16.h>

#define LSEQ 20000
#define DEG  16
#define F    128
#define ALPHA 0.2f

typedef __bf16 bf16x8 __attribute__((ext_vector_type(8)));
typedef float  f32x4  __attribute__((ext_vector_type(4)));

// W^T as bf16: wt[n*F + k] = bf16(W[k*F + n]). 32 KB, L1/L2-resident in gemm.
__global__ __launch_bounds__(256) void gat_wt(const float* __restrict__ W,
                                              __hip_bfloat16* __restrict__ wt)
{
    for (int i = blockIdx.x * 256 + threadIdx.x; i < F * F; i += 16 * 256) {
        const int k = i >> 7, n = i & (F - 1);
        wt[n * F + k] = __float2bfloat16(W[i]);
    }
}

// MFMA gemm: y16 = bf16(x @ W), s1 = (xW)·a1, s2 = (xW)·a2.
// One wave per 32-row stripe (2 A-fragment sets share each B load -> 2x MFMA
// density vs R3). A-frag: A[m=lane&15][k=(lane>>4)*8+j] (fp32 load + cvt).
// B-frag: W[k][n=lane&15] = wt[n][k] contiguous 16B.
// D: col=lane&15, row=(lane>>4)*4+reg (m89-verified layout).
__global__ __launch_bounds__(256) void gat_gemm(const float* __restrict__ x,
                                                const __hip_bfloat16* __restrict__ wt,
                                                const float* __restrict__ a,
                                                __hip_bfloat16* __restrict__ y16,
                                                float* __restrict__ s1,
                                                float* __restrict__ s2)
{
    const int lane = threadIdx.x & 63;
    const int wv   = (blockIdx.x * 256 + threadIdx.x) >> 6;  // global wave id
    const int row0 = wv * 32;
    const int m    = lane & 15;   // A row within half-stripe / D col
    const int q    = lane >> 4;   // quad group

    // A fragments: 2 half-stripes x 4 K-chunks (32 rows x 128 k per wave).
    bf16x8 afr[2][4];
    #pragma unroll
    for (int h = 0; h < 2; ++h) {
        const float* xr = x + (size_t)(row0 + h * 16 + m) * F + q * 8;
        #pragma unroll
        for (int kt = 0; kt < 4; ++kt) {
            const float4 q0 = *reinterpret_cast<const float4*>(xr + kt * 32);
            const float4 q1 = *reinterpret_cast<const float4*>(xr + kt * 32 + 4);
            bf16x8 f;
            f[0] = (__bf16)q0.x; f[1] = (__bf16)q0.y; f[2] = (__bf16)q0.z; f[3] = (__bf16)q0.w;
            f[4] = (__bf16)q1.x; f[5] = (__bf16)q1.y; f[6] = (__bf16)q1.z; f[7] = (__bf16)q1.w;
            afr[h][kt] = f;
        }
    }

    float p1[2][4] = {{0.f,0.f,0.f,0.f},{0.f,0.f,0.f,0.f}};
    float p2[2][4] = {{0.f,0.f,0.f,0.f},{0.f,0.f,0.f,0.f}};
    const __hip_bfloat16* wb = wt + (size_t)m * F + q * 8;

    #pragma unroll 2
    for (int ct = 0; ct < 8; ++ct) {
        union { uint4 u; bf16x8 v; } b[4];
        #pragma unroll
        for (int kt = 0; kt < 4; ++kt)
            b[kt].u = *reinterpret_cast<const uint4*>(wb + (size_t)ct * 16 * F + kt * 32);

        const int col = ct * 16 + m;
        const float a1v = a[col];
        const float a2v = a[F + col];

        #pragma unroll
        for (int h = 0; h < 2; ++h) {
            f32x4 acc = {0.f, 0.f, 0.f, 0.f};
            #pragma unroll
            for (int kt = 0; kt < 4; ++kt)
                acc = __builtin_amdgcn_mfma_f32_16x16x32_bf16(afr[h][kt], b[kt].v, acc, 0, 0, 0);
            #pragma unroll
            for (int r = 0; r < 4; ++r) {
                const int row = row0 + h * 16 + q * 4 + r;
                y16[(size_t)row * F + col] = __float2bfloat16(acc[r]);
                p1[h][r] = fmaf(acc[r], a1v, p1[h][r]);
                p2[h][r] = fmaf(acc[r], a2v, p2[h][r]);
            }
        }
    }

    // Reduce s1/s2 partials across the 16 cols held by lanes of each quad group.
    #pragma unroll
    for (int h = 0; h < 2; ++h) {
        #pragma unroll
        for (int r = 0; r < 4; ++r) {
            #pragma unroll
            for (int off = 1; off < 16; off <<= 1) {
                p1[h][r] += __shfl_xor(p1[h][r], off);
                p2[h][r] += __shfl_xor(p2[h][r], off);
            }
        }
    }
    if (m == 0) {
        #pragma unroll
        for (int h = 0; h < 2; ++h) {
            #pragma unroll
            for (int r = 0; r < 4; ++r) {
                s1[row0 + h * 16 + q * 4 + r] = p1[h][r];
                s2[row0 + h * 16 + q * 4 + r] = p2[h][r];
            }
        }
    }
}

// Kernel 2: one wave per (b,l). e_d = s1[adj_d] + s2[adj_0]; softmax over
// leaky_relu(e); out = elu(sum_d attn_d * y16[adj_d]). Lane holds 2 columns.
// Gathers batched up-front with readlane->SGPR addressing: 16 loads in
// flight, SALU address math, no per-iteration shuffles.
__global__ __launch_bounds__(256) void gat_attn(const int* __restrict__ adj,
                                                const __hip_bfloat16* __restrict__ y16,
                                                const float* __restrict__ s1,
                                                const float* __restrict__ s2,
                                                float* __restrict__ out)
{
    const int lane = threadIdx.x & 63;
    const int wid  = threadIdx.x >> 6;
    const int gl   = blockIdx.x * 4 + wid;      // flat (b,l)
    const int b    = gl / LSEQ;
    const int base = b * LSEQ;

    const int* adjp = adj + (size_t)gl * DEG;
    int av = (lane < DEG) ? adjp[lane] : 0;

    float sv = (lane < DEG) ? s1[base + av] : 0.f;
    const int a0 = __builtin_amdgcn_readlane(av, 0);
    const float e = sv + s2[base + a0];
    const float t = e > 0.f ? e : ALPHA * e;

    // softmax over lanes 0..15 (shuffles stay inside the 16-lane group)
    float m = t;
    #pragma unroll
    for (int off = 8; off; off >>= 1) m = fmaxf(m, __shfl_xor(m, off));
    float w = (lane < DEG) ? __expf(t - m) : 0.f;
    float p = w;
    #pragma unroll
    for (int off = 8; off; off >>= 1) p += __shfl_xor(p, off);
    const float attn = w / p;   // valid on lanes 0..15 (only those are read)

    // Batched gather: scalar (SGPR) row bases, 16 loads outstanding.
    unsigned int v[DEG];
    #pragma unroll
    for (int d = 0; d < DEG; ++d) {
        const int nb = __builtin_amdgcn_readlane(av, d);          // uniform
        const unsigned int* row =
            reinterpret_cast<const unsigned int*>(y16 + ((size_t)(base + nb) << 7));
        v[d] = row[lane];
    }

    float accx = 0.f, accy = 0.f;
    #pragma unroll
    for (int d = 0; d < DEG; ++d) {
        const float ad = __uint_as_float(
            __builtin_amdgcn_readlane(__float_as_uint(attn), d));  // uniform
        accx = fmaf(ad, __uint_as_float(v[d] << 16),          accx);
        accy = fmaf(ad, __uint_as_float(v[d] & 0xffff0000u),  accy);
    }
    const float ox = accx > 0.f ? accx : __expf(accx) - 1.f;
    const float oy = accy > 0.f ? accy : __expf(accy) - 1.f;
    *reinterpret_cast<float2*>(out + (size_t)gl * F + lane * 2) = make_float2(ox, oy);
}

extern "C" void kernel_launch(void* const* d_in, const int* in_sizes, int n_in,
                              void* d_out, int out_size, void* d_ws, size_t ws_size,
                              hipStream_t stream) {
    const float* x   = (const float*)d_in[0];
    const int*   adj = (const int*)d_in[1];
    const float* W   = (const float*)d_in[2];
    const float* a   = (const float*)d_in[3];
    float* out = (float*)d_out;

    const int BL = in_sizes[0] / F;   // bs*L = 80000

    __hip_bfloat16* y16 = (__hip_bfloat16*)d_ws;
    float* s1 = (float*)((char*)d_ws + (size_t)BL * F * sizeof(__hip_bfloat16));
    float* s2 = s1 + BL;
    __hip_bfloat16* wt = (__hip_bfloat16*)(s2 + BL);

    gat_wt  <<<16, 256, 0, stream>>>(W, wt);
    gat_gemm<<<BL / 128, 256, 0, stream>>>(x, wt, a, y16, s1, s2);
    gat_attn<<<BL / 4, 256, 0, stream>>>(adj, y16, s1, s2, out);
}